// Round 12
// baseline (473.306 us; speedup 1.0000x reference)
//
#include <hip/hip_runtime.h>
#include <math.h>
#include <stdint.h>

// Problem constants
#define BB    32
#define CIN   64
#define HH    32
#define WW    32
#define COUT  128
#define PP    1024      // HH*WW
#define OTILE 8         // output channels per block
#define PTILE 256       // pixels per block (4 waves x 64 px = 8 rows)
#define NPAD  12        // sorted theta list padded to 12 (pair-prefetch headroom)
#define TABN  160       // f-table knots
#define TROW  36        // tile row stride (34 cols + 2 slack)
#define TWSZ  148       // per-wave tile dwords (4*36 + dump + pad)

// Log2 domain: Z = (x - theta)*SCALEE. Table coord u = 8Z + 24 = x*MSC8 + thp,
// thp = 24 - theta*MSC8.
static constexpr float  MSC8     = 153.88747102815611f;   // inv_denom*log2(e)*8
static constexpr double M2Nd     = 0.26359713811572677;   // 2^-SBITS
static constexpr float  OUTSCALE = 2.7025482032898827e-05f; // ALPHA*R*ln2^2
static constexpr float  ZLO      = -3.0f;
static constexpr float  TABH     = 0.125f;
static constexpr float  IDXBIAS  = 24.0f;                 // -ZLO/h
static constexpr float  CUTBIAS  = 4.0f;                  // 24 - 8*ZCUT, ZCUT = 2.5

// ---------------- P0: prescale, koff-stuff, sort desc, pad ----------------
// ws layout: ws[(c*COUT + o)*NPAD + j] : thp sorted DESCENDING
__global__ __launch_bounds__(256) void sort_theta_kernel(
    const float* __restrict__ theta, float* __restrict__ ws)
{
    int gid = blockIdx.x * 256 + threadIdx.x;   // o*CIN + c (theta layout)
    if (gid >= COUT * CIN) return;
    int o = gid >> 6, c = gid & 63;
    const float* tg = theta + (size_t)gid * 9;
    float v[NPAD];
#pragma unroll
    for (int k = 0; k < 9; ++k) {
        float thp = fmaf(tg[k], -MSC8, IDXBIAS);
        int dy = k / 3, dx = k - 3 * dy;
        uint32_t koff = (uint32_t)(dy * TROW + dx);      // {0,1,2,36,37,38,72,73,74}
        v[k] = __uint_as_float((__float_as_uint(thp) & ~0x7Fu) | koff);
    }
    for (int i = 1; i < 9; ++i) {               // insertion sort DESCENDING
        float key = v[i];
        int j = i - 1;
        while (j >= 0 && v[j] < key) { v[j + 1] = v[j]; --j; }
        v[j + 1] = key;
    }
    float pad = __uint_as_float(__float_as_uint(-1e30f) & ~0x7Fu);  // inactive, koff=0
#pragma unroll
    for (int j = 9; j < NPAD; ++j) v[j] = pad;
    float* og = ws + (size_t)(c * COUT + o) * NPAD;
#pragma unroll
    for (int j = 0; j < NPAD; ++j) og[j] = v[j];
}

// ---------------- P1: per-(b, band, c) cut in thp units ----------------
__global__ __launch_bounds__(256) void bandcut_kernel(
    const float* __restrict__ x, float* __restrict__ bandcut)
{
    int t  = threadIdx.x;
    int bc = blockIdx.x;            // b*CIN + c
    const float4* xp = (const float4*)(x + (size_t)bc * PP);
    float4 v = xp[t];               // thread t: row t>>3, cols 4(t&7)..+3
    float m = fmaxf(fmaxf(v.x, v.y), fmaxf(v.z, v.w));
    m = fmaxf(m, __shfl_xor(m, 1));
    m = fmaxf(m, __shfl_xor(m, 2));
    m = fmaxf(m, __shfl_xor(m, 4));   // 8 threads of a row hold rowmax
    __shared__ float rmax[32];
    if ((t & 7) == 0) rmax[t >> 3] = m;
    __syncthreads();
    if (t < 16) {
        int r0 = max(2 * t - 1, 0), r3 = min(2 * t + 2, 31);
        float mm = rmax[r0];
        for (int r = r0 + 1; r <= r3; ++r) mm = fmaxf(mm, rmax[r]);
        mm = fmaxf(mm, 0.0f);         // zero-pad contributes xi = 0
        int b = bc >> 6, c = bc & 63;
        bandcut[((b * 16 + t) << 6) + c] = fmaf(mm, -MSC8, CUTBIAS);
    }
}

// ---------------- P2: coefficient table, fp64-evaluated ----------------
// tab[i] = (c0, c1), f(u) ~= c0 + c1*u on [i, i+1]; i=158 segment extrapolates
// the tail (slope = asymptote 2S*h to ~1e-6) — verified passing in R7/R9.
__global__ __launch_bounds__(256) void ftable_kernel(float2* __restrict__ tab)
{
    int i = threadIdx.x;
    if (i >= TABN) return;
    double Z0 = (double)ZLO + (double)TABH * i;
    double Z1 = Z0 + (double)TABH;
    auto fd = [](double Z) {
        double E = exp2(Z);
        double a = log2(1.0 + E);
        double b = log2(1.0 + E * M2Nd);
        return a * a - b * b;
    };
    double y0 = fd(Z0), y1 = fd(Z1);
    double c1 = y1 - y0;                 // per-u slope (segment width = 1 u)
    double c0 = y0 - (double)i * c1;
    tab[i] = make_float2((float)c0, (float)c1);
}

// ---------------- main kernel ----------------
__global__ __launch_bounds__(256) void nlconv_kernel(
    const float* __restrict__ x,        // [B, CIN, 32, 32]
    const float* __restrict__ wst,      // sorted thp [c][o][NPAD]
    const float* __restrict__ wcut,     // cutp [b][band][c]
    const float2* __restrict__ ftabg,   // coefficient table
    float* __restrict__ out)            // [B, COUT, 32, 32]
{
    __shared__ float  sxi[4 * TWSZ];    // per-wave 4x36 halo tiles + dump, 2368 B
    __shared__ float2 ftab[TABN];       // 1280 B

    const int t  = threadIdx.x;
    const int b  = blockIdx.x;
    const int pt = blockIdx.y;
    const int ot = blockIdx.z;
    const int w  = t >> 6;
    const int l  = t & 63;
    const int o0 = ot * OTILE;
    const int band = pt * 4 + w;
    const int rl = l >> 5, col = l & 31;

    if (t < TABN) ftab[t] = ftabg[t];

    // Opaque zero in a VGPR: added to theta byte-addresses so the compiler
    // cannot prove uniformity -> global_load (vmcnt) instead of s_load (lgkmcnt).
    // Keeps the in-loop lgkmcnt traffic pure-DS (in-order, precise waits).
    uint32_t voff = 0;
    asm volatile("" : "+v"(voff));

    // per-lane staging map: 3 entries e = l, l+64, l+128 over the 144-dword tile
    const int wbase = w * TWSZ;
    int   gofs[3];   // dword offset within a channel's 1024-px image
    float msc[3];    // MSC8 or 0 (halo/invalid)
    int   laddr[3];  // dword index into sxi
#pragma unroll
    for (int i = 0; i < 3; ++i) {
        int e  = l + 64 * i;
        bool valid = (e < 144);
        int ec = valid ? e : 144;           // dump slot for invalid third entries
        int r  = ec / TROW;
        int tc = ec - r * TROW;
        int grow = band * 2 - 1 + r;
        int gcol = tc - 1;
        bool inter = valid && (grow >= 0) && (grow < HH) && (gcol >= 0) && (gcol < WW) && (r < 4);
        gofs[i]  = (min(max(grow, 0), HH - 1) << 5) + min(max(gcol, 0), WW - 1);
        msc[i]   = inter ? MSC8 : 0.0f;
        laddr[i] = wbase + min(ec, TWSZ - 1);
    }

    // this wave's 64 channel cuts: lane c holds cutp[c]
    const float vcut = wcut[(size_t)((b * 16 + band) << 6) + l];

    // spread offsets for the ballot count (per-lane -> already VMEM)
    const int sp1 = (l >> 3) * NPAD + (l & 7);   // g = l>>3, j = l&7
    const int sp2 = (l & 7) * NPAD + 8;          // g = l&7,  j = 8

    const float* xc0 = x + (size_t)b * CIN * PP;
    const float* wso = wst + (size_t)o0 * NPAD;  // + c*COUT*NPAD
    const int xb = wbase + rl * TROW + col;      // body x base (dword)

    float acc[OTILE];
#pragma unroll
    for (int i = 0; i < OTILE; ++i) acc[i] = 0.0f;

    // prologue: xv(0) -> tile(0); xv <- c=1; f <- c=0
    float xv[3];
#pragma unroll
    for (int i = 0; i < 3; ++i) xv[i] = xc0[gofs[i]] * msc[i];
    float f1 = wso[sp1], f2 = wso[sp2];
#pragma unroll
    for (int i = 0; i < 3; ++i) sxi[laddr[i]] = xv[i];
#pragma unroll
    for (int i = 0; i < 3; ++i) xv[i] = xc0[PP + gofs[i]] * msc[i];

    __syncthreads();   // ftab ready (tiles are wave-private)

    for (int c = 0; c < CIN; ++c) {
        // theta base for this channel, with the opaque VGPR offset folded in:
        // loads below become global_load_dwordx2 (vmcnt), imm offsets <= 440 B
        const char* thv = (const char*)(wso + (size_t)c * (COUT * NPAD)) + voff;

        // pre-issue pair 0 of ALL 8 groups (8 loads in flight on vmcnt)
        float2 pc0[OTILE];
#pragma unroll
        for (int g = 0; g < 8; ++g)
            pc0[g] = *(const float2*)(thv + g * (NPAD * 4));

        const float cutp = __uint_as_float(
            (uint32_t)__builtin_amdgcn_readlane((int)__float_as_uint(vcut), c));
        unsigned long long mA = __ballot(f1 > cutp);
        unsigned long long mB = __ballot(f2 > cutp);

        // prefetch next c's spread values (per-lane VMEM)
        {
            int cn = min(c + 1, CIN - 1);
            const float* wsn = wso + (size_t)cn * (COUT * NPAD);
            f1 = wsn[sp1];
            f2 = wsn[sp2];
        }

#pragma unroll
        for (int g = 0; g < 8; ++g) {
            int cnt = (int)__popcll(mA & (0xFFull << (8 * g)))
                    + (int)((mB >> g) & 1ull);
            int np = (cnt + 1) >> 1;           // pair iterations (<=5)
            asm volatile("" : "+s"(np));       // opaque: loop stays a real loop
            const char* gthv = thv + g * (NPAD * 4);
            float2 pc = pc0[g];
            float a = acc[g];
#pragma unroll 1
            for (int j = 0; j < np; ++j) {
                float2 pn = *(const float2*)(gthv + 8 * j + 8);  // prefetch j+1 (vmcnt)
                // body A: ~9 VALU + 2 LDS; i=158 segment extrapolates the tail
                {
                    int   ko = (int)(__float_as_uint(pc.x) & 0x7Fu);
                    float xa = sxi[xb + ko];                   // ds_read
                    float u  = fmaxf(xa + pc.x, 0.0f);         // pads -> u=0 -> tv~f(-3)~0
                    int   i  = min((int)u, TABN - 2);
                    float2 cf = ftab[i];                       // ds_read_b64 (c0, c1)
                    a = fmaf(cf.y, u, a) + cf.x;               // a += c0 + c1*u
                }
                // body B
                {
                    int   ko = (int)(__float_as_uint(pc.y) & 0x7Fu);
                    float xa = sxi[xb + ko];
                    float u  = fmaxf(xa + pc.y, 0.0f);
                    int   i  = min((int)u, TABN - 2);
                    float2 cf = ftab[i];
                    a = fmaf(cf.y, u, a) + cf.x;
                }
                pc = pn;
            }
            acc[g] = a;
        }

        // stage tile(c+1) from xv, then prefetch xv(c+2)
#pragma unroll
        for (int i = 0; i < 3; ++i) sxi[laddr[i]] = xv[i];
        {
            int c2 = min(c + 2, CIN - 1);
            const float* xcn = xc0 + (size_t)c2 * PP;
#pragma unroll
            for (int i = 0; i < 3; ++i) xv[i] = xcn[gofs[i]] * msc[i];
        }
    }

    float* ob = out + ((size_t)b * COUT + o0) * PP + pt * PTILE + t;
#pragma unroll
    for (int o = 0; o < OTILE; ++o) {
        float v = acc[o] * OUTSCALE;
        v = fminf(fmaxf(v, 0.0f), 9.0f);
        ob[(size_t)o * PP] = v;
    }
}

extern "C" void kernel_launch(void* const* d_in, const int* in_sizes, int n_in,
                              void* d_out, int out_size, void* d_ws, size_t ws_size,
                              hipStream_t stream) {
    const float* x     = (const float*)d_in[0];  // [32,64,32,32]
    const float* theta = (const float*)d_in[1];  // [128,64,3,3]
    float* out         = (float*)d_out;          // [32,128,32,32]

    float*  ws_theta = (float*)d_ws;                               // 393,216 B
    float*  ws_cut   = ws_theta + (size_t)CIN * COUT * NPAD;       // 131,072 B
    float2* ws_tab   = (float2*)(ws_cut + (size_t)BB * 16 * 64);   //   1,280 B

    sort_theta_kernel<<<dim3((COUT * CIN + 255) / 256), dim3(256), 0, stream>>>(theta, ws_theta);
    bandcut_kernel<<<dim3(BB * CIN), dim3(256), 0, stream>>>(x, ws_cut);
    ftable_kernel<<<dim3(1), dim3(256), 0, stream>>>(ws_tab);

    dim3 grid(BB, PP / PTILE, COUT / OTILE);     // 32 x 4 x 16 = 2048 blocks
    nlconv_kernel<<<grid, dim3(256), 0, stream>>>(x, ws_theta, ws_cut, ws_tab, out);
}